// Round 1
// baseline (118.373 us; speedup 1.0000x reference)
//
#include <hip/hip_runtime.h>

#define IMG_W 1024
#define IMG_H 1024
#define TILE_W 64   // output tile width  (== blockDim.x)
#define TILE_H 16   // output tile height (blockDim.y=4, 4 px per thread)
#define LDS_W 68    // TILE_W + 4 halo
#define LDS_H 20    // TILE_H + 4 halo

__device__ __forceinline__ void ce(float &a, float &b) {
    float lo = fminf(a, b);
    float hi = fmaxf(a, b);
    a = lo; b = hi;
}

// Optimal 9-comparator sorting network for 5 elements (verified by merge argument):
// sort (3,4,2)->sorted3, pair (0,1), then merge.
__device__ __forceinline__ void sort5(float &a0, float &a1, float &a2, float &a3, float &a4) {
    ce(a0, a1); ce(a3, a4); ce(a2, a4); ce(a2, a3);
    ce(a0, a3); ce(a0, a2); ce(a1, a4); ce(a1, a3); ce(a1, a2);
}

__global__ __launch_bounds__(256) void median5x5_kernel(const float* __restrict__ x,
                                                        float* __restrict__ out) {
    __shared__ float tile[LDS_H][LDS_W];

    const int tx = threadIdx.x;          // 0..63
    const int ty = threadIdx.y;          // 0..3
    const int tid = ty * 64 + tx;
    const int plane = blockIdx.z;        // 0..B*C-1
    const float* src = x + (size_t)plane * IMG_H * IMG_W;

    const int gx0 = blockIdx.x * TILE_W - 2;
    const int gy0 = blockIdx.y * TILE_H - 2;

    // Stage tile (zero-padded at image borders), coalesced.
    #pragma unroll
    for (int idx = tid; idx < LDS_H * LDS_W; idx += 256) {
        int r = idx / LDS_W;
        int c = idx - r * LDS_W;
        int gy = gy0 + r;
        int gx = gx0 + c;
        float v = 0.0f;
        if ((unsigned)gy < IMG_H && (unsigned)gx < IMG_W)
            v = src[gy * IMG_W + gx];
        tile[r][c] = v;
    }
    __syncthreads();

    // Each thread: 4 vertically consecutive outputs at x = gx0+2+tx, y = gy0+2+ty*4+v.
    // Needs tile rows ty*4 .. ty*4+7, cols tx..tx+4. Sort all 8 row-windows once.
    float rs[8][5];
    #pragma unroll
    for (int i = 0; i < 8; ++i) {
        int tr = ty * 4 + i;
        float a0 = tile[tr][tx + 0];
        float a1 = tile[tr][tx + 1];
        float a2 = tile[tr][tx + 2];
        float a3 = tile[tr][tx + 3];
        float a4 = tile[tr][tx + 4];
        sort5(a0, a1, a2, a3, a4);
        rs[i][0] = a0; rs[i][1] = a1; rs[i][2] = a2; rs[i][3] = a3; rs[i][4] = a4;
    }

    const int ox = blockIdx.x * TILE_W + tx;
    const int oy0 = blockIdx.y * TILE_H + ty * 4;
    float* dst = out + (size_t)plane * IMG_H * IMG_W;

    #pragma unroll
    for (int v = 0; v < 4; ++v) {
        // Column-sort the 5x5 matrix of sorted rows rs[v..v+4].
        // Rows stay sorted (shearsort lemma) -> doubly-sorted matrix M.
        float M[5][5];
        #pragma unroll
        for (int j = 0; j < 5; ++j) {
            float a0 = rs[v + 0][j];
            float a1 = rs[v + 1][j];
            float a2 = rs[v + 2][j];
            float a3 = rs[v + 3][j];
            float a4 = rs[v + 4][j];
            sort5(a0, a1, a2, a3, a4);
            M[0][j] = a0; M[1][j] = a1; M[2][j] = a2; M[3][j] = a3; M[4][j] = a4;
        }
        // 13 median candidates (cells with <=12 guaranteed-below and <=12 guaranteed-above);
        // exactly 6 excluded cells are guaranteed below the median, so
        // answer = median (rank 6 of 13) of the candidates. Forgetful selection,
        // initial working set of 8 = four column-chain pairs (already ordered).
        float w0 = M[3][0], w1 = M[4][0], w2 = M[2][1], w3 = M[3][1];
        float w4 = M[1][2], w5 = M[2][2], w6 = M[0][3], w7 = M[1][3];
        // minmax8 (pairs pre-ordered): drop min (w0), max (w7)
        ce(w0, w2); ce(w4, w6); ce(w0, w4);
        ce(w1, w3); ce(w5, w7); ce(w3, w7);
        // 6 survivors + M[4][1] -> minmax7
        float e0 = w1, e1 = w2, e2 = w3, e3 = w4, e4 = w5, e5 = w6, e6 = M[4][1];
        ce(e0, e1); ce(e2, e3); ce(e4, e5);
        ce(e0, e2); ce(e4, e6); ce(e0, e4);   // min at e0
        ce(e1, e3); ce(e5, e6); ce(e3, e6);   // max at e6
        // 5 survivors + M[3][2] -> minmax6
        float f0 = e1, f1 = e2, f2 = e3, f3 = e4, f4 = e5, f5 = M[3][2];
        ce(f0, f1); ce(f2, f3); ce(f4, f5);
        ce(f0, f2); ce(f0, f4);               // min at f0
        ce(f1, f3); ce(f3, f5);               // max at f5
        // 4 survivors + M[2][3] -> minmax5
        float g0 = f1, g1 = f2, g2 = f3, g3 = f4, g4 = M[2][3];
        ce(g0, g1); ce(g2, g3);
        ce(g0, g2); ce(g0, g4);               // min at g0
        ce(g1, g3); ce(g3, g4);               // max at g4
        // 3 survivors + M[1][4] -> minmax4
        float h0 = g1, h1 = g2, h2 = g3, h3 = M[1][4];
        ce(h0, h1); ce(h2, h3); ce(h0, h2); ce(h1, h3);
        // 2 survivors + M[0][4] -> median of 3 = answer
        float med = __builtin_amdgcn_fmed3f(h1, h2, M[0][4]);

        dst[(size_t)(oy0 + v) * IMG_W + ox] = med;
    }
}

extern "C" void kernel_launch(void* const* d_in, const int* in_sizes, int n_in,
                              void* d_out, int out_size, void* d_ws, size_t ws_size,
                              hipStream_t stream) {
    const float* x = (const float*)d_in[0];
    float* out = (float*)d_out;
    const int planes = in_sizes[0] / (IMG_H * IMG_W);   // B*C = 8
    dim3 grid(IMG_W / TILE_W, IMG_H / TILE_H, planes);
    dim3 block(64, 4);
    median5x5_kernel<<<grid, block, 0, stream>>>(x, out);
}

// Round 2
// 114.364 us; speedup vs baseline: 1.0351x; 1.0351x over previous
//
#include <hip/hip_runtime.h>

#define IMG_W 1024
#define IMG_H 1024
#define TILE_W 64   // output tile width  (== blockDim.x)
#define TILE_H 32   // output tile height (blockDim.y=4, 8 px per thread)
#define LDS_W 68    // TILE_W + 4 halo
#define LDS_H 36    // TILE_H + 4 halo

__device__ __forceinline__ void ce(float &a, float &b) {
    float lo = fminf(a, b);
    float hi = fmaxf(a, b);
    a = lo; b = hi;
}

// 9-CE optimal full sort of 5 (validated round 1, absmax 0).
__device__ __forceinline__ void sort5(float &a0, float &a1, float &a2, float &a3, float &a4) {
    ce(a0, a1); ce(a3, a4); ce(a2, a4); ce(a2, a3);
    ce(a0, a3); ce(a0, a2); ce(a1, a4); ce(a1, a3); ce(a1, a2);
}

// 7-CE: lo0 <= lo1 are the two smallest of 5; {t0,t1,t2} is the top-3 SET.
// Net: ce01 ce23 ce02 ce13 ce12 ce04 ce14 (hand-verified incl. a4-extreme cases).
__device__ __forceinline__ void bot2_top3set(float a0, float a1, float a2, float a3, float a4,
                                             float &lo0, float &lo1,
                                             float &t0, float &t1, float &t2) {
    ce(a0, a1); ce(a2, a3); ce(a0, a2); ce(a1, a3); ce(a1, a2); ce(a0, a4); ce(a1, a4);
    lo0 = a0; lo1 = a1; t0 = a2; t1 = a3; t2 = a4;
}

// 7-CE mirror: hi0 = max, hi1 = 2nd-max; {b0,b1,b2} is the bottom-3 SET.
__device__ __forceinline__ void top2_bot3set(float a0, float a1, float a2, float a3, float a4,
                                             float &hi0, float &hi1,
                                             float &b0, float &b1, float &b2) {
    ce(a3, a4); ce(a1, a2); ce(a2, a4); ce(a1, a3); ce(a2, a3); ce(a0, a4); ce(a0, a3);
    hi0 = a4; hi1 = a3; b0 = a0; b1 = a1; b2 = a2;
}

// 6-CE: {m0,m1,m2} is the middle-3 SET (global min and max removed).
__device__ __forceinline__ void mid3set(float a0, float a1, float a2, float a3, float a4,
                                        float &m0, float &m1, float &m2) {
    ce(a0, a1); ce(a2, a3); ce(a0, a2); ce(a1, a3); ce(a0, a4); ce(a4, a3);
    m0 = a1; m1 = a2; m2 = a4;
}

__global__ __launch_bounds__(256, 2) void median5x5_kernel(const float* __restrict__ x,
                                                           float* __restrict__ out) {
    __shared__ float tile[LDS_H][LDS_W];

    const int tx = threadIdx.x;          // 0..63
    const int ty = threadIdx.y;          // 0..3
    const int tid = ty * 64 + tx;
    const int plane = blockIdx.z;        // 0..B*C-1
    const float* src = x + (size_t)plane * IMG_H * IMG_W;

    const int gx0 = blockIdx.x * TILE_W - 2;
    const int gy0 = blockIdx.y * TILE_H - 2;

    // Stage tile (zero-padded at image borders), coalesced b32.
    for (int idx = tid; idx < LDS_H * LDS_W; idx += 256) {
        int r = idx / LDS_W;
        int c = idx - r * LDS_W;
        int gy = gy0 + r;
        int gx = gx0 + c;
        float v = 0.0f;
        if ((unsigned)gy < IMG_H && (unsigned)gx < IMG_W)
            v = src[gy * IMG_W + gx];
        tile[r][c] = v;
    }
    __syncthreads();

    // Rolling window of 5 sorted horizontal row-windows (25 live regs).
    // Thread outputs rows oy = by*32 + ty*8 + v, v = 0..7; window tile rows ty*8+v .. +4.
    const int base = ty * 8;
    float S[5][5];
    #pragma unroll
    for (int i = 0; i < 4; ++i) {
        int tr = base + i;
        float a0 = tile[tr][tx + 0], a1 = tile[tr][tx + 1], a2 = tile[tr][tx + 2],
              a3 = tile[tr][tx + 3], a4 = tile[tr][tx + 4];
        sort5(a0, a1, a2, a3, a4);
        S[i][0] = a0; S[i][1] = a1; S[i][2] = a2; S[i][3] = a3; S[i][4] = a4;
    }

    const int ox = blockIdx.x * TILE_W + tx;
    const int oy0 = blockIdx.y * TILE_H + ty * 8;
    float* dst = out + (size_t)plane * IMG_H * IMG_W;

    #pragma unroll
    for (int v = 0; v < 8; ++v) {
        // Bring in the new bottom row of the window (slot rotation; column
        // selections below are order-invariant so rotation order is irrelevant).
        {
            int tr = base + 4 + v;
            float a0 = tile[tr][tx + 0], a1 = tile[tr][tx + 1], a2 = tile[tr][tx + 2],
                  a3 = tile[tr][tx + 3], a4 = tile[tr][tx + 4];
            sort5(a0, a1, a2, a3, a4);
            int s = (4 + v) % 5;
            S[s][0] = a0; S[s][1] = a1; S[s][2] = a2; S[s][3] = a3; S[s][4] = a4;
        }

        // Column-wise partial selections of the row-sorted 5x5 matrix.
        // Candidate cells (doubly-sorted dominance argument, validated round 1):
        // col0 ranks {3,4}, col1 {2,3,4}, col2 {1,2,3}, col3 {0,1,2}, col4 {0,1}.
        float A, B;                    // col0: A = 2nd-max <= B = max
        { float u0, u1, u2;
          top2_bot3set(S[0][0], S[1][0], S[2][0], S[3][0], S[4][0], B, A, u0, u1, u2); }
        float c1a, c1b, c1c;           // col1 top-3 set
        { float l0, l1;
          bot2_top3set(S[0][1], S[1][1], S[2][1], S[3][1], S[4][1], l0, l1, c1a, c1b, c1c); }
        float c2a, c2b, c2c;           // col2 middle-3 set
        mid3set(S[0][2], S[1][2], S[2][2], S[3][2], S[4][2], c2a, c2b, c2c);
        float c3a, c3b, c3c;           // col3 bottom-3 set
        { float h0, h1;
          top2_bot3set(S[0][3], S[1][3], S[2][3], S[3][3], S[4][3], h0, h1, c3a, c3b, c3c); }
        float D, E;                    // col4: D = min <= E = 2nd-min
        { float t0, t1, t2;
          bot2_top3set(S[0][4], S[1][4], S[2][4], S[3][4], S[4][4], D, E, t0, t1, t2); }

        // Forgetful selection: median (rank 6) of the 13 candidates.
        // minmax8 on {A,B,D,E,c1a,c1b,c3a,c3b}; (A<=B, D<=E already ordered).
        ce(c1a, c1b); ce(c3a, c3b);
        ce(A, D); ce(c1a, c3a); ce(A, c1a);        // A = min8 (drop)
        ce(B, E); ce(c1b, c3b); ce(E, c3b);        // c3b = max8 (drop)
        // survivors: B, D, E, c1a, c1b, c3a  (+ c1c) -> minmax7
        float e0 = B, e1 = D, e2 = E, e3 = c1a, e4 = c1b, e5 = c3a, e6 = c1c;
        ce(e0, e1); ce(e2, e3); ce(e4, e5);
        ce(e0, e2); ce(e4, e6); ce(e0, e4);        // e0 = min (drop)
        ce(e1, e3); ce(e5, e6); ce(e3, e6);        // e6 = max (drop)
        // survivors e1..e5 (+ c2a) -> minmax6
        float f0 = e1, f1 = e2, f2 = e3, f3 = e4, f4 = e5, f5 = c2a;
        ce(f0, f1); ce(f2, f3); ce(f4, f5);
        ce(f0, f2); ce(f0, f4);                    // f0 = min (drop)
        ce(f1, f3); ce(f3, f5);                    // f5 = max (drop)
        // survivors f1..f4 (+ c2b) -> minmax5
        float g0 = f1, g1 = f2, g2 = f3, g3 = f4, g4 = c2b;
        ce(g0, g1); ce(g2, g3);
        ce(g0, g2); ce(g0, g4);                    // g0 = min (drop)
        ce(g1, g3); ce(g3, g4);                    // g4 = max (drop)
        // survivors g1,g2,g3 (+ c2c) -> minmax4
        float h0 = g1, h1 = g2, h2 = g3, h3 = c2c;
        ce(h0, h1); ce(h2, h3); ce(h0, h2); ce(h1, h3);
        // survivors h1,h2 (+ c3c) -> median of 3
        float med = __builtin_amdgcn_fmed3f(h1, h2, c3c);

        dst[(size_t)(oy0 + v) * IMG_W + ox] = med;
    }
}

extern "C" void kernel_launch(void* const* d_in, const int* in_sizes, int n_in,
                              void* d_out, int out_size, void* d_ws, size_t ws_size,
                              hipStream_t stream) {
    const float* x = (const float*)d_in[0];
    float* out = (float*)d_out;
    const int planes = in_sizes[0] / (IMG_H * IMG_W);   // B*C = 8
    dim3 grid(IMG_W / TILE_W, IMG_H / TILE_H, planes);
    dim3 block(64, 4);
    median5x5_kernel<<<grid, block, 0, stream>>>(x, out);
}

// Round 3
// 113.860 us; speedup vs baseline: 1.0396x; 1.0044x over previous
//
#include <hip/hip_runtime.h>

#define IMG_W 1024
#define IMG_H 1024
#define TILE_W 64   // output tile width  (== blockDim.x)
#define TILE_H 32   // output tile height (blockDim.y=4, 8 px per thread)
#define LDS_W 68    // TILE_W + 4 halo
#define LDS_H 36    // TILE_H + 4 halo

__device__ __forceinline__ void ce(float &a, float &b) {
    float lo = fminf(a, b);
    float hi = fmaxf(a, b);
    a = lo; b = hi;
}

// 9-CE optimal full sort of 5 (validated: absmax 0, rounds 1-2).
__device__ __forceinline__ void sort5(float &a0, float &a1, float &a2, float &a3, float &a4) {
    ce(a0, a1); ce(a3, a4); ce(a2, a4); ce(a2, a3);
    ce(a0, a3); ce(a0, a2); ce(a1, a4); ce(a1, a3); ce(a1, a2);
}

// Median of the 25-window given 5 row-sorted rows (row order irrelevant).
// Column partial selections + forgetful-13 tail; byte-identical math to the
// round-2 kernel which validated absmax = 0 over 8.39M random windows.
__device__ __forceinline__ float median_sel(
    float a0, float a1, float a2, float a3, float a4,
    float b0, float b1, float b2, float b3, float b4,
    float c0, float c1, float c2, float c3, float c4,
    float d0, float d1, float d2, float d3, float d4,
    float e0, float e1, float e2, float e3, float e4)
{
    // col0 candidate ranks {3,4}: A = 2nd-max, B = max (7-CE top2 net; bottom-3 DCE'd)
    float A, B;
    { float x0 = a0, x1 = b0, x2 = c0, x3 = d0, x4 = e0;
      ce(x3, x4); ce(x1, x2); ce(x2, x4); ce(x1, x3); ce(x2, x3); ce(x0, x4); ce(x0, x3);
      B = x4; A = x3; }
    // col1 candidate ranks {2,3,4}: top-3 set (7-CE; bottom-2 DCE'd)
    float c1a, c1b, c1c;
    { float x0 = a1, x1 = b1, x2 = c1, x3 = d1, x4 = e1;
      ce(x0, x1); ce(x2, x3); ce(x0, x2); ce(x1, x3); ce(x1, x2); ce(x0, x4); ce(x1, x4);
      c1a = x2; c1b = x3; c1c = x4; }
    // col2 candidate ranks {1,2,3}: middle-3 set (6-CE)
    float c2a, c2b, c2c;
    { float x0 = a2, x1 = b2, x2 = c2, x3 = d2, x4 = e2;
      ce(x0, x1); ce(x2, x3); ce(x0, x2); ce(x1, x3); ce(x0, x4); ce(x4, x3);
      c2a = x1; c2b = x2; c2c = x4; }
    // col3 candidate ranks {0,1,2}: bottom-3 set (7-CE; top-2 DCE'd)
    float c3a, c3b, c3c;
    { float x0 = a3, x1 = b3, x2 = c3, x3 = d3, x4 = e3;
      ce(x3, x4); ce(x1, x2); ce(x2, x4); ce(x1, x3); ce(x2, x3); ce(x0, x4); ce(x0, x3);
      c3a = x0; c3b = x1; c3c = x2; }
    // col4 candidate ranks {0,1}: D = min, E = 2nd-min (7-CE; top-3 DCE'd)
    float D, E;
    { float x0 = a4, x1 = b4, x2 = c4, x3 = d4, x4 = e4;
      ce(x0, x1); ce(x2, x3); ce(x0, x2); ce(x1, x3); ce(x1, x2); ce(x0, x4); ce(x1, x4);
      D = x0; E = x1; }

    // Forgetful selection: median (rank 6) of the 13 candidates.
    ce(c1a, c1b); ce(c3a, c3b);
    ce(A, D); ce(c1a, c3a); ce(A, c1a);        // A = min8 (drop)
    ce(B, E); ce(c1b, c3b); ce(E, c3b);        // c3b = max8 (drop)
    float p0 = B, p1 = D, p2 = E, p3 = c1a, p4 = c1b, p5 = c3a, p6 = c1c;
    ce(p0, p1); ce(p2, p3); ce(p4, p5);
    ce(p0, p2); ce(p4, p6); ce(p0, p4);        // p0 = min7 (drop)
    ce(p1, p3); ce(p5, p6); ce(p3, p6);        // p6 = max7 (drop)
    float f0 = p1, f1 = p2, f2 = p3, f3 = p4, f4 = p5, f5 = c2a;
    ce(f0, f1); ce(f2, f3); ce(f4, f5);
    ce(f0, f2); ce(f0, f4);                    // f0 = min6 (drop)
    ce(f1, f3); ce(f3, f5);                    // f5 = max6 (drop)
    float g0 = f1, g1 = f2, g2 = f3, g3 = f4, g4 = c2b;
    ce(g0, g1); ce(g2, g3);
    ce(g0, g2); ce(g0, g4);                    // g0 = min5 (drop)
    ce(g1, g3); ce(g3, g4);                    // g4 = max5 (drop)
    float h0 = g1, h1 = g2, h2 = g3, h3 = c2c;
    ce(h0, h1); ce(h2, h3); ce(h0, h2); ce(h1, h3);
    return __builtin_amdgcn_fmed3f(h1, h2, c3c);
}

__global__ __launch_bounds__(256, 2) void median5x5_kernel(const float* __restrict__ x,
                                                           float* __restrict__ out) {
    __shared__ float tile[LDS_H][LDS_W];

    const int tx = threadIdx.x;          // 0..63
    const int ty = threadIdx.y;          // 0..3
    const int tid = ty * 64 + tx;
    const int plane = blockIdx.z;        // 0..B*C-1
    const float* src = x + (size_t)plane * IMG_H * IMG_W;

    const int gx0 = blockIdx.x * TILE_W - 2;
    const int gy0 = blockIdx.y * TILE_H - 2;

    // Stage tile (zero-padded at image borders), coalesced b32.
    for (int idx = tid; idx < LDS_H * LDS_W; idx += 256) {
        int r = idx / LDS_W;
        int c = idx - r * LDS_W;
        int gy = gy0 + r;
        int gx = gx0 + c;
        float v = 0.0f;
        if ((unsigned)gy < IMG_H && (unsigned)gx < IMG_W)
            v = src[gy * IMG_W + gx];
        tile[r][c] = v;
    }
    __syncthreads();

    const int base = ty * 8;
    const int ox = blockIdx.x * TILE_W + tx;
    const int oy0 = blockIdx.y * TILE_H + ty * 8;
    float* dst = out + (size_t)plane * IMG_H * IMG_W;

    // Rolling window: 25 NAMED scalars (no arrays -> no scratch demotion).
    // Row slots SA..SE; row base+i lives in slot i%5. Slot order within the
    // window is irrelevant (median_sel is row-order-invariant).
    float A0, A1, A2, A3, A4, B0, B1, B2, B3, B4, C0, C1, C2, C3, C4,
          D0, D1, D2, D3, D4, E0, E1, E2, E3, E4;

#define LOADSORT(P0, P1, P2, P3, P4, tr) do {                                  \
        P0 = tile[tr][tx + 0]; P1 = tile[tr][tx + 1]; P2 = tile[tr][tx + 2];   \
        P3 = tile[tr][tx + 3]; P4 = tile[tr][tx + 4];                          \
        sort5(P0, P1, P2, P3, P4);                                             \
    } while (0)

    LOADSORT(A0, A1, A2, A3, A4, base + 0);
    LOADSORT(B0, B1, B2, B3, B4, base + 1);
    LOADSORT(C0, C1, C2, C3, C4, base + 2);
    LOADSORT(D0, D1, D2, D3, D4, base + 3);

#define STEP(P0, P1, P2, P3, P4, tr, vv) do {                                  \
        LOADSORT(P0, P1, P2, P3, P4, tr);                                      \
        dst[(size_t)(oy0 + (vv)) * IMG_W + ox] = median_sel(                   \
            A0, A1, A2, A3, A4, B0, B1, B2, B3, B4, C0, C1, C2, C3, C4,        \
            D0, D1, D2, D3, D4, E0, E1, E2, E3, E4);                           \
    } while (0)

    STEP(E0, E1, E2, E3, E4, base + 4,  0);
    STEP(A0, A1, A2, A3, A4, base + 5,  1);
    STEP(B0, B1, B2, B3, B4, base + 6,  2);
    STEP(C0, C1, C2, C3, C4, base + 7,  3);
    STEP(D0, D1, D2, D3, D4, base + 8,  4);
    STEP(E0, E1, E2, E3, E4, base + 9,  5);
    STEP(A0, A1, A2, A3, A4, base + 10, 6);
    STEP(B0, B1, B2, B3, B4, base + 11, 7);

#undef STEP
#undef LOADSORT
}

extern "C" void kernel_launch(void* const* d_in, const int* in_sizes, int n_in,
                              void* d_out, int out_size, void* d_ws, size_t ws_size,
                              hipStream_t stream) {
    const float* x = (const float*)d_in[0];
    float* out = (float*)d_out;
    const int planes = in_sizes[0] / (IMG_H * IMG_W);   // B*C = 8
    dim3 grid(IMG_W / TILE_W, IMG_H / TILE_H, planes);
    dim3 block(64, 4);
    median5x5_kernel<<<grid, block, 0, stream>>>(x, out);
}

// Round 4
// 96.882 us; speedup vs baseline: 1.2218x; 1.1752x over previous
//
#include <hip/hip_runtime.h>

#define IMG_W 1024
#define IMG_H 1024

// Packed 2 x f16: one VGPR holds the same window-position value for two
// horizontally adjacent output pixels. v_pk_min_f16 / v_pk_max_f16 do one
// comparator-exchange half for both pixels in a single instruction.
typedef _Float16 h2 __attribute__((ext_vector_type(2)));

__device__ __forceinline__ h2 mn(h2 a, h2 b) { return __builtin_elementwise_min(a, b); }
__device__ __forceinline__ h2 mx(h2 a, h2 b) { return __builtin_elementwise_max(a, b); }
__device__ __forceinline__ void ce(h2 &a, h2 &b) { h2 t = mn(a, b); b = mx(a, b); a = t; }
// median-of-3, packed (4 ops; case-verified for all orderings)
__device__ __forceinline__ h2 med3p(h2 a, h2 b, h2 c) {
    return mx(mn(a, b), mn(mx(a, b), c));
}
// 9-CE optimal sort5 (validated absmax=0 rounds 1-3)
__device__ __forceinline__ void sort5(h2 &a0, h2 &a1, h2 &a2, h2 &a3, h2 &a4) {
    ce(a0, a1); ce(a3, a4); ce(a2, a4); ce(a2, a3);
    ce(a0, a3); ce(a0, a2); ce(a1, a4); ce(a1, a3); ce(a1, a2);
}
// 5-CE sort4
__device__ __forceinline__ void sort4(h2 &a, h2 &b, h2 &c, h2 &d) {
    ce(a, b); ce(c, d); ce(a, c); ce(b, d); ce(b, c);
}

__device__ __forceinline__ h2 bch2(unsigned u) { return __builtin_bit_cast(h2, u); }

// A sorted 5-wide horizontal window row (packed for 2 pixels).
struct Row { h2 a, b, c, d, e; };

// Load one tile row's 6 halfwords (3 dwords) and build + sort the 5 packed
// window values. Funnel shifts fuse to v_alignbit_b32.
__device__ __forceinline__ Row load_sort_row(const unsigned* __restrict__ ldsrow, int tx) {
    unsigned d0 = ldsrow[tx], d1 = ldsrow[tx + 1], d2 = ldsrow[tx + 2];
    h2 p0 = bch2(d0);
    h2 p1 = bch2((d0 >> 16) | (d1 << 16));
    h2 p2 = bch2(d1);
    h2 p3 = bch2((d1 >> 16) | (d2 << 16));
    h2 p4 = bch2(d2);
    sort5(p0, p1, p2, p3, p4);
    return {p0, p1, p2, p3, p4};
}

// Forgetful selection: median (rank 6) of the 13 candidates. Identical network
// to the round-2/3 tail (validated absmax=0) minus the two ordering CEs, which
// are no-ops here because (A<=B),(c1a<=c1b),(c3a<=c3b),(D<=E) hold by construction.
__device__ __forceinline__ h2 tail13(h2 A, h2 B, h2 c1a, h2 c1b, h2 c1c,
                                     h2 c2a, h2 c2b, h2 c2c,
                                     h2 c3a, h2 c3b, h2 c3c, h2 D, h2 E) {
    ce(A, D); ce(c1a, c3a); ce(A, c1a);        // A = min8 (drop)
    ce(B, E); ce(c1b, c3b); ce(E, c3b);        // c3b = max8 (drop)
    h2 e0 = B, e1 = D, e2 = E, e3 = c1a, e4 = c1b, e5 = c3a, e6 = c1c;
    ce(e0, e1); ce(e2, e3); ce(e4, e5);
    ce(e0, e2); ce(e4, e6); ce(e0, e4);        // e0 = min7 (drop)
    ce(e1, e3); ce(e5, e6); ce(e3, e6);        // e6 = max7 (drop)
    h2 f0 = e1, f1 = e2, f2 = e3, f3 = e4, f4 = e5, f5 = c2a;
    ce(f0, f1); ce(f2, f3); ce(f4, f5);
    ce(f0, f2); ce(f0, f4);                    // f0 = min6 (drop)
    ce(f1, f3); ce(f3, f5);                    // f5 = max6 (drop)
    h2 g0 = f1, g1 = f2, g2 = f3, g3 = f4, g4 = c2b;
    ce(g0, g1); ce(g2, g3);
    ce(g0, g2); ce(g0, g4);                    // g0 = min5 (drop)
    ce(g1, g3); ce(g3, g4);                    // g4 = max5 (drop)
    h2 h0 = g1, h1 = g2, h2_ = g3, h3 = c2c;
    ce(h0, h1); ce(h2_, h3); ce(h0, h2_); ce(h1, h3);
    return med3p(h1, h2_, c3c);
}

// Two vertically adjacent windows sharing 4 rows (rb,rc,rd,re). Per column:
// sort4 the shared values once, then extract each window's candidates from
// sorted4 + its private row (ra for window-lo, rf for window-hi):
//   top2 of 5:   B=max(s3,x), A=max(s2,min(s3,x))          [3 ops]
//   top3 set:    {s2, s3, max(s1,x)}                       [1 op]
//   mid3 set:    {s1, s2, med3(s0,x,s3)}                   [4 ops]
//   bot3 set:    {s0, s1, min(s2,x)}                       [1 op]
//   bot2 of 5:   D=min(s0,x), E=min(s1,max(s0,x))          [3 ops]
// (each formula case-verified for x below/inside/above the sorted4 range)
__device__ __forceinline__ void pair_medians(const Row &rb, const Row &rc, const Row &rd,
                                             const Row &re, const Row &ra, const Row &rf,
                                             h2 &out_lo, h2 &out_hi) {
    h2 s0, s1, s2, s3;
    // col0: candidate ranks {3,4} -> (A,B), A<=B
    s0 = rb.a; s1 = rc.a; s2 = rd.a; s3 = re.a; sort4(s0, s1, s2, s3);
    h2 Bl = mx(s3, ra.a), Al = mx(s2, mn(s3, ra.a));
    h2 Bh = mx(s3, rf.a), Ah = mx(s2, mn(s3, rf.a));
    // col1: top-3 set
    s0 = rb.b; s1 = rc.b; s2 = rd.b; s3 = re.b; sort4(s0, s1, s2, s3);
    h2 c1al = s2, c1bl = s3, c1cl = mx(s1, ra.b);
    h2 c1ah = s2, c1bh = s3, c1ch = mx(s1, rf.b);
    // col2: middle-3 set
    s0 = rb.c; s1 = rc.c; s2 = rd.c; s3 = re.c; sort4(s0, s1, s2, s3);
    h2 c2al = s1, c2bl = s2, c2cl = med3p(s0, ra.c, s3);
    h2 c2ah = s1, c2bh = s2, c2ch = med3p(s0, rf.c, s3);
    // col3: bottom-3 set
    s0 = rb.d; s1 = rc.d; s2 = rd.d; s3 = re.d; sort4(s0, s1, s2, s3);
    h2 c3al = s0, c3bl = s1, c3cl = mn(s2, ra.d);
    h2 c3ah = s0, c3bh = s1, c3ch = mn(s2, rf.d);
    // col4: candidate ranks {0,1} -> (D,E), D<=E
    s0 = rb.e; s1 = rc.e; s2 = rd.e; s3 = re.e; sort4(s0, s1, s2, s3);
    h2 Dl = mn(s0, ra.e), El = mn(s1, mx(s0, ra.e));
    h2 Dh = mn(s0, rf.e), Eh = mn(s1, mx(s0, rf.e));

    out_lo = tail13(Al, Bl, c1al, c1bl, c1cl, c2al, c2bl, c2cl, c3al, c3bl, c3cl, Dl, El);
    out_hi = tail13(Ah, Bh, c1ah, c1bh, c1ch, c2ah, c2bh, c2ch, c3ah, c3bh, c3ch, Dh, Eh);
}

// Block: 32x8 threads. Lane covers 2 adjacent output columns x 8 output rows
// (16 px/thread). Tile: 64x64 outputs, LDS 68 rows x 35 dwords (70 f16) = 9520 B.
#define LDS_DW 35
__global__ __launch_bounds__(256, 4) void median5x5_kernel(const float* __restrict__ x,
                                                           float* __restrict__ out) {
    __shared__ unsigned lds[68][LDS_DW];

    const int tx = threadIdx.x;          // 0..31
    const int ty = threadIdx.y;          // 0..7
    const int tid = ty * 32 + tx;
    const int plane = blockIdx.z;
    const float* src = x + (size_t)plane * IMG_H * IMG_W;

    const int gx0 = blockIdx.x * 64 - 2;   // halfword h maps input col gx0+h
    const int gy0 = blockIdx.y * 64 - 2;

    // Stage: f32 global -> packed f16 LDS (cvt_pkrtz; RTZ is monotone so the
    // selected median equals f16(true median), err <= ulp ~ 0.004 < 0.0264 tol).
    for (unsigned idx = tid; idx < 68u * LDS_DW; idx += 256) {
        unsigned r = idx / LDS_DW;
        unsigned dc = idx - r * LDS_DW;
        int gy = gy0 + (int)r;
        int gxa = gx0 + 2 * (int)dc;
        int gxb = gxa + 1;
        bool rowok = (unsigned)gy < (unsigned)IMG_H;
        float a = (rowok && (unsigned)gxa < (unsigned)IMG_W) ? src[gy * IMG_W + gxa] : 0.0f;
        float b = (rowok && (unsigned)gxb < (unsigned)IMG_W) ? src[gy * IMG_W + gxb] : 0.0f;
        lds[r][dc] = __builtin_bit_cast(unsigned, __builtin_amdgcn_cvt_pkrtz(a, b));
    }
    __syncthreads();

    const int base = ty * 8;               // first output row (tile-local) of this thread
    // Rolling 6-row register window over tile rows base+0 .. base+11.
    Row S0 = load_sort_row(&lds[base + 0][0], tx);
    Row S1 = load_sort_row(&lds[base + 1][0], tx);
    Row S2 = load_sort_row(&lds[base + 2][0], tx);
    Row S3 = load_sort_row(&lds[base + 3][0], tx);
    Row S4 = load_sort_row(&lds[base + 4][0], tx);
    Row S5 = load_sort_row(&lds[base + 5][0], tx);

    float* dst = out + (size_t)plane * IMG_H * IMG_W
               + (size_t)(blockIdx.y * 64 + base) * IMG_W + blockIdx.x * 64 + 2 * tx;
    h2 mlo, mhi;

#define EMIT(vv, m) do {                                                       \
        float2 o; o.x = (float)(m).x; o.y = (float)(m).y;                      \
        *reinterpret_cast<float2*>(dst + (size_t)(vv) * IMG_W) = o;            \
    } while (0)

    // pair 0: windows rows 0-4 / 1-5 (shared 1-4)
    pair_medians(S1, S2, S3, S4, S0, S5, mlo, mhi);
    EMIT(0, mlo); EMIT(1, mhi);
    S0 = load_sort_row(&lds[base + 6][0], tx);
    S1 = load_sort_row(&lds[base + 7][0], tx);
    // pair 1: windows rows 2-6 / 3-7 (shared 3-6)
    pair_medians(S3, S4, S5, S0, S2, S1, mlo, mhi);
    EMIT(2, mlo); EMIT(3, mhi);
    S2 = load_sort_row(&lds[base + 8][0], tx);
    S3 = load_sort_row(&lds[base + 9][0], tx);
    // pair 2: windows rows 4-8 / 5-9 (shared 5-8)
    pair_medians(S5, S0, S1, S2, S4, S3, mlo, mhi);
    EMIT(4, mlo); EMIT(5, mhi);
    S4 = load_sort_row(&lds[base + 10][0], tx);
    S5 = load_sort_row(&lds[base + 11][0], tx);
    // pair 3: windows rows 6-10 / 7-11 (shared 7-10)
    pair_medians(S1, S2, S3, S4, S0, S5, mlo, mhi);
    EMIT(6, mlo); EMIT(7, mhi);
#undef EMIT
}

extern "C" void kernel_launch(void* const* d_in, const int* in_sizes, int n_in,
                              void* d_out, int out_size, void* d_ws, size_t ws_size,
                              hipStream_t stream) {
    const float* x = (const float*)d_in[0];
    float* out = (float*)d_out;
    const int planes = in_sizes[0] / (IMG_H * IMG_W);   // B*C = 8
    dim3 grid(IMG_W / 64, IMG_H / 64, planes);
    dim3 block(32, 8);
    median5x5_kernel<<<grid, block, 0, stream>>>(x, out);
}